// Round 13
// baseline (231.254 us; speedup 1.0000x reference)
//
#include <hip/hip_runtime.h>
#include <cstdint>
#include <cstddef>

#define N1 4096
#define N2 16384
#define C1 256
#define C2 128
#define HH 256
#define K1 384
#define BQ 32768          // B*N2 total queries
#define KPAD 392          // LDS k-stride (bf16 elems): 16B-aligned, banks balanced

typedef float  f32x4  __attribute__((ext_vector_type(4)));
typedef __bf16 bf16x8 __attribute__((ext_vector_type(8)));
typedef __bf16 bf16x4 __attribute__((ext_vector_type(4)));

// Exact reference RN sequence for squared distance.
__device__ __forceinline__ float exact_dd(float ux, float uy, float uz,
                                          float su, float4 p) {
  float dot = __fadd_rn(__fadd_rn(__fmul_rn(ux, p.x), __fmul_rn(uy, p.y)),
                        __fmul_rn(uz, p.z));
  return __builtin_fmaf(dot, -2.0f, __fadd_rn(su, p.w));
}

// Lexicographic (d, idx) insert == stable top-k semantics (ties -> lower idx).
#define LEXINS(da, db, dc, ia, ib, ic, dd, jj)                                 \
  {                                                                            \
    bool ca = ((dd) < (da)) || ((dd) == (da) && (jj) < (ia));                  \
    bool cb = ((dd) < (db)) || ((dd) == (db) && (jj) < (ib));                  \
    bool cc = ((dd) < (dc)) || ((dd) == (dc) && (jj) < (ic));                  \
    dc = cb ? (db) : (cc ? (dd) : (dc));                                       \
    ic = cb ? (ib) : (cc ? (jj) : (ic));                                       \
    db = ca ? (da) : (cb ? (dd) : (db));                                       \
    ib = ca ? (ia) : (cb ? (jj) : (ib));                                       \
    da = ca ? (dd) : (da);                                                     \
    ia = ca ? (jj) : (ia);                                                     \
  }

// Sorted top-4 maintain on float keys: 1 min + 3 med3.
#define KMIN4(K1_, K2_, K3_, K4_, x)                                           \
  {                                                                            \
    float n1 = fminf((K1_), (x));                                              \
    float n2 = __builtin_amdgcn_fmed3f((K1_), (x), (K2_));                     \
    float n3 = __builtin_amdgcn_fmed3f((K2_), (x), (K3_));                     \
    float n4 = __builtin_amdgcn_fmed3f((K3_), (x), (K4_));                     \
    K1_ = n1; K2_ = n2; K3_ = n3; K4_ = n4;                                    \
  }

// Per-point scalar distance + key + keyed insert (key low 12 bits = index).
#define POINTQ(ux, uy, uz, su, px, py, pz, pw, jj, Ka, Kb, Kc, Kd)             \
  {                                                                            \
    float dot_ = __fadd_rn(                                                    \
        __fadd_rn(__fmul_rn((ux), (px)), __fmul_rn((uy), (py))),               \
        __fmul_rn((uz), (pz)));                                                \
    float dd_ = __builtin_fmaf(dot_, -2.0f, __fadd_rn((su), (pw)));            \
    float xk_ = __uint_as_float((__float_as_uint(dd_) & 0xFFFFF000u) |         \
                                ((unsigned)(jj) & 0x00000FFFu));               \
    KMIN4(Ka, Kb, Kc, Kd, xk_);                                                \
  }

// ---------------------------------------------------------------------------
// k_prep: pts4 = (x,y,z,|k|^2) exact RN; W1/W2 -> bf16; BN folded.
// ---------------------------------------------------------------------------
__global__ __launch_bounds__(256) void k_prep(
    const float* __restrict__ p1,
    const float* __restrict__ W1, const float* __restrict__ W2,
    const float* __restrict__ b1, const float* __restrict__ g1,
    const float* __restrict__ be1, const float* __restrict__ mm1,
    const float* __restrict__ vv1,
    const float* __restrict__ b2, const float* __restrict__ g2,
    const float* __restrict__ be2, const float* __restrict__ mm2,
    const float* __restrict__ vv2,
    float4* __restrict__ pts4,
    __bf16* __restrict__ W1b, __bf16* __restrict__ W2b,
    float* __restrict__ scsh) {
  int idx = blockIdx.x * 256 + threadIdx.x;      // grid 384*256 = 98304
  if (idx < HH * K1) W1b[idx] = (__bf16)W1[idx];
  if (idx < HH * HH) W2b[idx] = (__bf16)W2[idx];
  if (idx < 2 * N1) {
    int b = idx >> 12, j = idx & (N1 - 1);
    const float* p = p1 + (size_t)b * 3 * N1;
    float x = p[j], y = p[N1 + j], z = p[2 * N1 + j];
    float sk = __fadd_rn(__fadd_rn(__fmul_rn(x, x), __fmul_rn(y, y)),
                         __fmul_rn(z, z));
    pts4[idx] = make_float4(x, y, z, sk);
  }
  if (idx < HH) {
    float sc = g1[idx] / sqrtf(vv1[idx] + 1e-3f);
    scsh[idx]          = sc;
    scsh[HH + idx]     = fmaf(b1[idx] - mm1[idx], sc, be1[idx]);
    float s2 = g2[idx] / sqrtf(vv2[idx] + 1e-3f);
    scsh[2 * HH + idx] = s2;
    scsh[3 * HH + idx] = fmaf(b2[idx] - mm2[idx], s2, be2[idx]);
  }
}

// ---------------------------------------------------------------------------
// k_nn: single-kernel exact 3-NN + weights. 8 sub-lanes per query.
// 1024 blocks x 256 threads = 32 queries/block; sub-lane s scans points
// j = 8k+s (wave reads 128B contiguous, 8-way broadcast; pts4 is 64KB/batch,
// L1/L2-hot). Keyed top-4 per sub-lane (scalar math — pk f32 has no
// throughput benefit on gfx950 and ~4x issue cost), 3-round shfl_xor
// butterfly -> exact global keyed top-4 in-wave (no keybuf, no k_merge).
// Flag on masked k3==k4 collision (the only case keyed selection can differ
// from exact stable top-3); flagged 8-lane groups (flag is group-uniform, so
// shuffle sources stay active) do a FULL exact rescan + lexicographic
// butterfly — strictly safer than candidate-only fallback. sub==0 recomputes
// exact RN dd for the winners and applies the exact reference weight math.
// ---------------------------------------------------------------------------
__global__ __launch_bounds__(256) void k_nn(
    const float* __restrict__ p2, const float4* __restrict__ pts4,
    float* __restrict__ wbuf, int* __restrict__ ibuf) {
#pragma clang fp contract(off)
  const int t = threadIdx.x;
  const int sub = t & 7;
  const int qi = blockIdx.x * 32 + (t >> 3);   // 1024 blocks -> 32768 queries
  const int b  = qi >> 14;
  const int n  = qi & (N2 - 1);

  const float* p2b = p2 + (size_t)b * 3 * N2;
  float ux = p2b[n], uy = p2b[N2 + n], uz = p2b[2 * N2 + n];
  float su = __fadd_rn(__fadd_rn(__fmul_rn(ux, ux), __fmul_rn(uy, uy)),
                       __fmul_rn(uz, uz));

  const float4* pb = pts4 + (size_t)b * N1;
  float Ka = 3.0e38f, Kb = 3.0e38f, Kc = 3.0e38f, Kd = 3.0e38f;
#pragma unroll 8
  for (int k = 0; k < 512; ++k) {
    int j = (k << 3) + sub;
    float4 p = pb[j];
    POINTQ(ux, uy, uz, su, p.x, p.y, p.z, p.w, j, Ka, Kb, Kc, Kd);
  }

  // butterfly keyed merge across the 8 sub-lanes -> exact global keyed top-4
#pragma unroll
  for (int msk = 1; msk <= 4; msk <<= 1) {
    float ea = __shfl_xor(Ka, msk, 64), eb = __shfl_xor(Kb, msk, 64);
    float ec = __shfl_xor(Kc, msk, 64), ed = __shfl_xor(Kd, msk, 64);
    KMIN4(Ka, Kb, Kc, Kd, ea);
    KMIN4(Ka, Kb, Kc, Kd, eb);
    KMIN4(Ka, Kb, Kc, Kd, ec);
    KMIN4(Ka, Kb, Kc, Kd, ed);
  }
  bool flag = (__float_as_uint(Kc) >> 12) == (__float_as_uint(Kd) >> 12);

  float da = 3.0e38f, db = 3.0e38f, dc = 3.0e38f;
  int ia = 0x7fffffff, ib = 0x7fffffff, ic = 0x7fffffff;
  if (flag) {
    // exact full rescan (group-uniform branch; ~0.1-1% of query groups)
    for (int k = 0; k < 512; ++k) {
      int j = (k << 3) + sub;
      float4 p = pb[j];
      float dd = exact_dd(ux, uy, uz, su, p);
      LEXINS(da, db, dc, ia, ib, ic, dd, j);
    }
#pragma unroll
    for (int msk = 1; msk <= 4; msk <<= 1) {
      float ea = __shfl_xor(da, msk, 64), eb = __shfl_xor(db, msk, 64),
            ec = __shfl_xor(dc, msk, 64);
      int ja = __shfl_xor(ia, msk, 64), jb = __shfl_xor(ib, msk, 64),
          jc = __shfl_xor(ic, msk, 64);
      LEXINS(da, db, dc, ia, ib, ic, ea, ja);
      LEXINS(da, db, dc, ia, ib, ic, eb, jb);
      LEXINS(da, db, dc, ia, ib, ic, ec, jc);
    }
  }

  if (sub == 0) {
    if (!flag) {
      ia = (int)(__float_as_uint(Ka) & 0xFFFu);
      ib = (int)(__float_as_uint(Kb) & 0xFFFu);
      ic = (int)(__float_as_uint(Kc) & 0xFFFu);
      da = exact_dd(ux, uy, uz, su, pb[ia]);
      db = exact_dd(ux, uy, uz, su, pb[ib]);
      dc = exact_dd(ux, uy, uz, su, pb[ic]);
    }
    // exact reference weight arithmetic
    float qa = fmaxf(da, 0.0f), qb = fmaxf(db, 0.0f), qc = fmaxf(dc, 0.0f);
    qa = fmaxf(__fmul_rn(qa, qa), 1e-10f);
    qb = fmaxf(__fmul_rn(qb, qb), 1e-10f);
    qc = fmaxf(__fmul_rn(qc, qc), 1e-10f);
    float va = __fdiv_rn(1.0f, qa);
    float vb = __fdiv_rn(1.0f, qb);
    float vc = __fdiv_rn(1.0f, qc);
    float s = __fadd_rn(__fadd_rn(va, vb), vc);
    wbuf[qi]          = __fdiv_rn(va, s);
    wbuf[BQ + qi]     = __fdiv_rn(vb, s);
    wbuf[2 * BQ + qi] = __fdiv_rn(vc, s);
    ibuf[qi]          = ia;
    ibuf[BQ + qi]     = ib;
    ibuf[2 * BQ + qi] = ic;
  }
}

// ---------------------------------------------------------------------------
// k_transpose: features1 [B,C1,N1] -> f1T [B,N1,C1].
// ---------------------------------------------------------------------------
__global__ __launch_bounds__(256) void k_transpose(
    const float* __restrict__ f1, float* __restrict__ f1T) {
  __shared__ float tile[64][65];
  const int bx = blockIdx.x;            // B * 4(ct) * 64(nt) = 512
  const int b = bx >> 8;
  const int rest = bx & 255;
  const int ct = rest >> 6;
  const int ntb = (rest & 63) << 6;
  const int t = threadIdx.x;
  const int ln = t & 63, g = t >> 6;

  const float* src = f1 + ((size_t)b * C1 + ct * 64) * N1 + ntb;
  for (int k = 0; k < 16; ++k) {
    int c = (k << 2) + g;
    tile[c][ln] = src[(size_t)c * N1 + ln];
  }
  __syncthreads();
  float* dst = f1T + ((size_t)b * N1 + ntb) * C1 + ct * 64;
  for (int k = 0; k < 16; ++k) {
    int nn = (k << 2) + g;
    dst[(size_t)nn * C1 + ln] = tile[ln][nn];
  }
}

// ---------------------------------------------------------------------------
// k_fused: gather+interp -> bf16 LDS [col][k] -> MFMA GEMM1 -> BN1+ReLU ->
// bf16 LDS h -> MFMA GEMM2 -> BN2+ReLU -> out (fp32).
// 512 threads = 8 waves; wave wv owns 32 output rows; 64-col tile.
// ---------------------------------------------------------------------------
__global__ __launch_bounds__(512) void k_fused(
    const float* __restrict__ f1T, const float* __restrict__ f2,
    const float* __restrict__ wbuf, const int* __restrict__ ibuf,
    const __bf16* __restrict__ W1b, const __bf16* __restrict__ W2b,
    const float* __restrict__ scsh, float* __restrict__ out) {
  __shared__ __bf16 sX[64 * KPAD];       // 49KB; x for GEMM1, then h for GEMM2
  const int t = threadIdx.x;
  const int bx = blockIdx.x;
  const int b = bx >> 8;
  const int n0 = (bx & 255) << 6;

  // ---- Phase A1: interp C1 channels; 8 threads/col x 8 float4 groups ----
  {
    const int nn = t >> 3, qq = t & 7;
    const int gi = b * N2 + n0 + nn;
    const float w0 = wbuf[gi], w1 = wbuf[BQ + gi], w2 = wbuf[2 * BQ + gi];
    const int i0 = ibuf[gi], i1 = ibuf[BQ + gi], i2 = ibuf[2 * BQ + gi];
    const float4* r0 = (const float4*)(f1T + ((size_t)b * N1 + i0) * C1);
    const float4* r1 = (const float4*)(f1T + ((size_t)b * N1 + i1) * C1);
    const float4* r2 = (const float4*)(f1T + ((size_t)b * N1 + i2) * C1);
#pragma unroll 4
    for (int m = 0; m < 8; ++m) {
      int idx4 = (qq << 3) + m;          // 0..63
      float4 a = r0[idx4], c4 = r1[idx4], d4 = r2[idx4];
      bf16x4 v;
      v[0] = (__bf16)fmaf(w0, a.x, fmaf(w1, c4.x, w2 * d4.x));
      v[1] = (__bf16)fmaf(w0, a.y, fmaf(w1, c4.y, w2 * d4.y));
      v[2] = (__bf16)fmaf(w0, a.z, fmaf(w1, c4.z, w2 * d4.z));
      v[3] = (__bf16)fmaf(w0, a.w, fmaf(w1, c4.w, w2 * d4.w));
      *(bf16x4*)&sX[nn * KPAD + (idx4 << 2)] = v;
    }
  }
  // ---- Phase A2: features2 channels (k = 256..383) ----
  {
    const int col = t & 63, g = t >> 6;
    const float* f2b = f2 + (size_t)b * C2 * N2 + n0 + col;
#pragma unroll
    for (int m = 0; m < 4; ++m) {
      int c4 = (g << 4) + (m << 2);
      bf16x4 v;
      v[0] = (__bf16)f2b[(size_t)(c4 + 0) * N2];
      v[1] = (__bf16)f2b[(size_t)(c4 + 1) * N2];
      v[2] = (__bf16)f2b[(size_t)(c4 + 2) * N2];
      v[3] = (__bf16)f2b[(size_t)(c4 + 3) * N2];
      *(bf16x4*)&sX[col * KPAD + 256 + c4] = v;
    }
  }
  __syncthreads();

  const int l  = t & 63;
  const int wv = __builtin_amdgcn_readfirstlane(t >> 6);
  const int ob = wv << 5;                // 32 rows per wave
  const int lm = l & 15, lg = l >> 4;

  f32x4 acc[2][4];
#pragma unroll
  for (int mt = 0; mt < 2; ++mt)
#pragma unroll
    for (int nt = 0; nt < 4; ++nt) acc[mt][nt] = (f32x4)0.0f;

  // ---- GEMM1: K = 384 (12 k-steps) ----
  for (int ks = 0; ks < 12; ++ks) {
    bf16x8 af[2], bfr[4];
#pragma unroll
    for (int mt = 0; mt < 2; ++mt)
      af[mt] = *(const bf16x8*)(W1b + (size_t)(ob + mt * 16 + lm) * K1 +
                                ks * 32 + lg * 8);
#pragma unroll
    for (int nt = 0; nt < 4; ++nt)
      bfr[nt] = *(const bf16x8*)&sX[(nt * 16 + lm) * KPAD + ks * 32 + lg * 8];
#pragma unroll
    for (int mt = 0; mt < 2; ++mt)
#pragma unroll
      for (int nt = 0; nt < 4; ++nt)
        acc[mt][nt] = __builtin_amdgcn_mfma_f32_16x16x32_bf16(
            af[mt], bfr[nt], acc[mt][nt], 0, 0, 0);
  }
  __syncthreads();

  // ---- BN1 + ReLU -> h (bf16) back into sX ----
#pragma unroll
  for (int mt = 0; mt < 2; ++mt) {
    int rb = ob + mt * 16 + lg * 4;     // h-channel base (GEMM1 output row)
    float4 sc4 = *(const float4*)(scsh + rb);
    float4 sh4 = *(const float4*)(scsh + HH + rb);
#pragma unroll
    for (int nt = 0; nt < 4; ++nt) {
      int colc = nt * 16 + lm;
      bf16x4 v;
      v[0] = (__bf16)fmaxf(fmaf(acc[mt][nt][0], sc4.x, sh4.x), 0.0f);
      v[1] = (__bf16)fmaxf(fmaf(acc[mt][nt][1], sc4.y, sh4.y), 0.0f);
      v[2] = (__bf16)fmaxf(fmaf(acc[mt][nt][2], sc4.z, sh4.z), 0.0f);
      v[3] = (__bf16)fmaxf(fmaf(acc[mt][nt][3], sc4.w, sh4.w), 0.0f);
      *(bf16x4*)&sX[colc * KPAD + rb] = v;
    }
  }
  __syncthreads();

  // ---- GEMM2: K = 256 (8 k-steps) ----
  f32x4 ac2[2][4];
#pragma unroll
  for (int mt = 0; mt < 2; ++mt)
#pragma unroll
    for (int nt = 0; nt < 4; ++nt) ac2[mt][nt] = (f32x4)0.0f;
  for (int ks = 0; ks < 8; ++ks) {
    bf16x8 af[2], bfr[4];
#pragma unroll
    for (int mt = 0; mt < 2; ++mt)
      af[mt] = *(const bf16x8*)(W2b + (size_t)(ob + mt * 16 + lm) * HH +
                                ks * 32 + lg * 8);
#pragma unroll
    for (int nt = 0; nt < 4; ++nt)
      bfr[nt] = *(const bf16x8*)&sX[(nt * 16 + lm) * KPAD + ks * 32 + lg * 8];
#pragma unroll
    for (int mt = 0; mt < 2; ++mt)
#pragma unroll
      for (int nt = 0; nt < 4; ++nt)
        ac2[mt][nt] = __builtin_amdgcn_mfma_f32_16x16x32_bf16(
            af[mt], bfr[nt], ac2[mt][nt], 0, 0, 0);
  }

  // ---- BN2 + ReLU -> out (fp32) ----
  float* outb = out + (size_t)b * HH * N2 + n0;
#pragma unroll
  for (int mt = 0; mt < 2; ++mt) {
    int rb = ob + mt * 16 + lg * 4;
    float4 sc4 = *(const float4*)(scsh + 2 * HH + rb);
    float4 sh4 = *(const float4*)(scsh + 3 * HH + rb);
#pragma unroll
    for (int nt = 0; nt < 4; ++nt) {
      int colc = nt * 16 + lm;
      outb[(size_t)(rb + 0) * N2 + colc] =
          fmaxf(fmaf(ac2[mt][nt][0], sc4.x, sh4.x), 0.0f);
      outb[(size_t)(rb + 1) * N2 + colc] =
          fmaxf(fmaf(ac2[mt][nt][1], sc4.y, sh4.y), 0.0f);
      outb[(size_t)(rb + 2) * N2 + colc] =
          fmaxf(fmaf(ac2[mt][nt][2], sc4.z, sh4.z), 0.0f);
      outb[(size_t)(rb + 3) * N2 + colc] =
          fmaxf(fmaf(ac2[mt][nt][3], sc4.w, sh4.w), 0.0f);
    }
  }
}

// ---------------------------------------------------------------------------
extern "C" void kernel_launch(void* const* d_in, const int* in_sizes, int n_in,
                              void* d_out, int out_size, void* d_ws, size_t ws_size,
                              hipStream_t stream) {
  const float* p1  = (const float*)d_in[0];
  const float* p2  = (const float*)d_in[1];
  const float* f1  = (const float*)d_in[2];
  const float* f2  = (const float*)d_in[3];
  const float* W1  = (const float*)d_in[4];
  const float* bb1 = (const float*)d_in[5];
  const float* g1  = (const float*)d_in[6];
  const float* be1 = (const float*)d_in[7];
  const float* mm1 = (const float*)d_in[8];
  const float* vv1 = (const float*)d_in[9];
  const float* W2  = (const float*)d_in[10];
  const float* bb2 = (const float*)d_in[11];
  const float* g2  = (const float*)d_in[12];
  const float* be2 = (const float*)d_in[13];
  const float* mm2 = (const float*)d_in[14];
  const float* vv2 = (const float*)d_in[15];
  float* out = (float*)d_out;

  // ws layout (~9.6 MB, no aliasing; keybuf/pts8/k_merge eliminated)
  char* ws = (char*)d_ws;
  float*  f1T  = (float*)(ws);                 // 8,388,608 B
  float*  wbuf = (float*)(ws + 8388608);       //   393,216 B
  int*    ibuf = (int*)  (ws + 8781824);       //   393,216 B
  float4* pts4 = (float4*)(ws + 9175040);      //   131,072 B
  __bf16* W1b  = (__bf16*)(ws + 9306112);      //   196,608 B
  __bf16* W2b  = (__bf16*)(ws + 9502720);      //   131,072 B
  float*  scsh = (float*)(ws + 9633792);       //     4,096 B

  k_prep<<<384, 256, 0, stream>>>(p1, W1, W2,
                                  bb1, g1, be1, mm1, vv1,
                                  bb2, g2, be2, mm2, vv2,
                                  pts4, W1b, W2b, scsh);
  k_nn<<<1024, 256, 0, stream>>>(p2, pts4, wbuf, ibuf);
  k_transpose<<<512, 256, 0, stream>>>(f1, f1T);
  k_fused<<<512, 512, 0, stream>>>(f1T, f2, wbuf, ibuf, W1b, W2b, scsh, out);
}